// Round 1
// baseline (1276.289 us; speedup 1.0000x reference)
//
#include <hip/hip_runtime.h>
#include <cmath>

#define NB 8
#define NN 4096
#define DF 128
#define NH 4
#define NJ 32
#define NK 128
#define NTOT (NB*NN)          // 32768
#define ETOT 524288           // 8 * 4096 * 16
#define BPB (NH*NB*NJ)        // 1024
#define DHID 256
#define NCLS 16

#define FP_SCALE 4194304.0    // 2^22 fixed-point for deterministic score scatter
#define FP_INV   (1.0/4194304.0)

// ---------------- init ----------------
__global__ void k0_init(int* deg_i, int* iscore, int* cnt, int* fill) {
    int t = blockIdx.x * blockDim.x + threadIdx.x;
    if (t < NTOT * NH) iscore[t] = 0;
    if (t < NTOT) deg_i[t] = 0;
    if (t < BPB) { cnt[t] = 0; fill[t] = 0; }
}

// deg = 1 + in-degree (int, exact, deterministic)
__global__ void k1_deg(const int* __restrict__ ei, int* deg_i) {
    int e = blockIdx.x * blockDim.x + threadIdx.x;
    if (e >= ETOT) return;
    atomicAdd(&deg_i[ei[ETOT + e]], 1);
}

// scores_pre = x_flat @ W_rank  (double accum: closest to exact, minimizes sort-flip risk)
__global__ void k2_scores(const float* __restrict__ x, const float* __restrict__ wr,
                          float* __restrict__ scores_pre) {
    int t = blockIdx.x * blockDim.x + threadIdx.x;
    if (t >= NTOT * NH) return;
    int g = t >> 2, hh = t & 3;
    const float* xr = x + (size_t)g * DF;
    double acc = 0.0;
    for (int d0 = 0; d0 < DF; ++d0) acc += (double)xr[d0] * (double)wr[d0 * NH + hh];
    scores_pre[t] = (float)acc;
}

// x_appd init with diagonal term x/deg
__global__ void k2b_xinit(const float* __restrict__ x, const int* __restrict__ deg_i,
                          float* __restrict__ xapp) {
    int t = blockIdx.x * blockDim.x + threadIdx.x;
    if (t >= NTOT * 32) return;
    int g = t >> 5, c0 = (t & 31) * 4;
    float dg = (float)(1 + deg_i[g]);
    float4 v = *(const float4*)(x + (size_t)g * DF + c0);
    v.x /= dg; v.y /= dg; v.z /= dg; v.w /= dg;
    *(float4*)(xapp + (size_t)g * DF + c0) = v;
}

// score scatter: out[dst] += w * scores_pre[src]  (fixed-point int atomics -> deterministic)
__global__ void k3_scatter_scores(const int* __restrict__ ei, const int* __restrict__ deg_i,
                                  const float* __restrict__ scores_pre, int* iscore) {
    int t = blockIdx.x * blockDim.x + threadIdx.x;
    if (t >= ETOT * NH) return;
    int e = t >> 2, hh = t & 3;
    int s = ei[e], d = ei[ETOT + e];
    double w = 1.0 / sqrt((double)((1 + deg_i[s]) * (1 + deg_i[d])));
    double term = w * (double)scores_pre[s * NH + hh];
    atomicAdd(&iscore[d * NH + hh], __double2int_rn(term * FP_SCALE));
}

// x_appd scatter: xapp[dst,:] += w * x[src,:]  (float HW atomics; only smooth consumers)
__global__ void k4_scatter_x(const int* __restrict__ ei, const int* __restrict__ deg_i,
                             const float* __restrict__ x, float* __restrict__ xapp) {
    int t = blockIdx.x * blockDim.x + threadIdx.x;
    if (t >= ETOT * 32) return;
    int e = t >> 5, c0 = (t & 31) * 4;
    int s = ei[e], d = ei[ETOT + e];
    float w = (float)(1.0 / sqrt((double)((1 + deg_i[s]) * (1 + deg_i[d]))));
    float4 v = *(const float4*)(x + (size_t)s * DF + c0);
    float* o = xapp + (size_t)d * DF + c0;
    unsafeAtomicAdd(o + 0, w * v.x);
    unsafeAtomicAdd(o + 1, w * v.y);
    unsafeAtomicAdd(o + 2, w * v.z);
    unsafeAtomicAdd(o + 3, w * v.w);
}

// G = concat(x, xapp) @ W1   (32768 x 256) -- 16-row tiles, f32
__global__ __launch_bounds__(256) void kg_gemm(const float* __restrict__ x,
                                               const float* __restrict__ xapp,
                                               const float* __restrict__ W1,
                                               float* __restrict__ G) {
    __shared__ float fs[16 * 256];
    int g0 = blockIdx.x * 16;
    int tid = threadIdx.x;
    for (int t = tid; t < 16 * 64; t += 256) {
        int r = t >> 6, q4 = t & 63;
        int g = g0 + r;
        const float* src = (q4 < 32) ? (x + (size_t)g * DF + q4 * 4)
                                     : (xapp + (size_t)g * DF + (q4 - 32) * 4);
        ((float4*)fs)[t] = *(const float4*)src;
    }
    __syncthreads();
    int c = tid;
    float acc[16];
#pragma unroll
    for (int ii = 0; ii < 16; ++ii) acc[ii] = 0.f;
    for (int q4 = 0; q4 < 64; ++q4) {
        int q = q4 * 4;
        float w0 = W1[(q + 0) * DHID + c];
        float w1 = W1[(q + 1) * DHID + c];
        float w2 = W1[(q + 2) * DHID + c];
        float w3 = W1[(q + 3) * DHID + c];
#pragma unroll
        for (int ii = 0; ii < 16; ++ii) {
            float4 m4 = *(const float4*)(fs + ii * 256 + q);
            acc[ii] = fmaf(m4.x, w0, acc[ii]);
            acc[ii] = fmaf(m4.y, w1, acc[ii]);
            acc[ii] = fmaf(m4.z, w2, acc[ii]);
            acc[ii] = fmaf(m4.w, w3, acc[ii]);
        }
    }
#pragma unroll
    for (int ii = 0; ii < 16; ++ii) G[((size_t)(g0 + ii)) * DHID + c] = acc[ii];
}

// per-(b,head) stable bitonic sort of 4096 scores (desc score, asc idx) + pos/val/tgt
__global__ __launch_bounds__(1024) void k5_sort(const float* __restrict__ scores_pre,
                                                const int* __restrict__ iscore,
                                                const int* __restrict__ deg_i,
                                                int* order, int* pos, int* tgt, float* val) {
    __shared__ float key[NN];
    __shared__ int   idx[NN];
    int bid = blockIdx.x;            // b*4 + hh
    int b = bid >> 2, hh = bid & 3;
    int tid = threadIdx.x;
    for (int p = tid; p < NN; p += 1024) {
        int g = b * NN + p;
        float dg = (float)(1 + deg_i[g]);
        key[p] = scores_pre[g * NH + hh] / dg + (float)((double)iscore[g * NH + hh] * FP_INV);
        idx[p] = p;
    }
    __syncthreads();
    for (int size = 2; size <= NN; size <<= 1) {
        for (int stride = size >> 1; stride > 0; stride >>= 1) {
            for (int p = tid; p < NN; p += 1024) {
                int q = p ^ stride;
                if (q > p) {
                    float kp = key[p], kq = key[q];
                    int ip = idx[p], iq = idx[q];
                    bool before_qp = (kq > kp) || (kq == kp && iq < ip);
                    bool asc = ((p & size) == 0);
                    if (asc ? before_qp : !before_qp) {
                        key[p] = kq; key[q] = kp; idx[p] = iq; idx[q] = ip;
                    }
                }
            }
            __syncthreads();
        }
    }
    for (int p = tid; p < NN; p += 1024) {
        int o = idx[p];
        order[bid * NN + p] = o;
        pos[bid * NN + o] = p;
        float sc = key[p];
        val[bid * NN + p] = 1.0f / (1.0f + expf(-sc));
    }
    __syncthreads();
    for (int p = tid; p < NN; p += 1024) {
        int base0 = p & ~(NK - 1);
        int me = idx[p];
        int r = 0;
        for (int s2 = 0; s2 < NK; ++s2) r += (idx[base0 + s2] < me) ? 1 : 0;
        tgt[bid * NN + p] = r;
    }
}

// count kept (same-block) edge-head pairs per block
__global__ void k6_count(const int* __restrict__ ei, const int* __restrict__ pos, int* cnt) {
    int e = blockIdx.x * blockDim.x + threadIdx.x;
    if (e >= ETOT) return;
    int s = ei[e], d = ei[ETOT + e];
    int b = s >> 12, sl = s & 4095, dl = d & 4095;
#pragma unroll
    for (int hh = 0; hh < NH; ++hh) {
        int ph = (b << 2) | hh;
        int ps = pos[ph * NN + sl], pd = pos[ph * NN + dl];
        if ((ps >> 7) == (pd >> 7))
            atomicAdd(&cnt[((hh * NB + b) * NJ) + (ps >> 7)], 1);
    }
}

__global__ __launch_bounds__(1024) void k7_scan(const int* __restrict__ cnt, int* base) {
    __shared__ int sh[BPB];
    int t = threadIdx.x;
    sh[t] = cnt[t];
    __syncthreads();
    for (int off = 1; off < BPB; off <<= 1) {
        int v = (t >= off) ? sh[t - off] : 0;
        __syncthreads();
        sh[t] += v;
        __syncthreads();
    }
    base[t + 1] = sh[t];
    if (t == 0) base[0] = 0;
}

__global__ void k8_fill(const int* __restrict__ ei, const int* __restrict__ pos,
                        const int* __restrict__ base, int* fill, unsigned* elist) {
    int e = blockIdx.x * blockDim.x + threadIdx.x;
    if (e >= ETOT) return;
    int s = ei[e], d = ei[ETOT + e];
    int b = s >> 12, sl = s & 4095, dl = d & 4095;
#pragma unroll
    for (int hh = 0; hh < NH; ++hh) {
        int ph = (b << 2) | hh;
        int ps = pos[ph * NN + sl], pd = pos[ph * NN + dl];
        if ((ps >> 7) == (pd >> 7)) {
            int bpid = ((hh * NB + b) * NJ) + (ps >> 7);
            int k2 = atomicAdd(&fill[bpid], 1);
            elist[base[bpid] + k2] = (unsigned)((ps & 127) | ((pd & 127) << 16));
        }
    }
}

// per-block: Hh rows = relu(sum_edges coef * G[node_d,:]), mean over 128 rows, @ W_out
__global__ __launch_bounds__(256) void k9_block(const float* __restrict__ G,
                                                const int* __restrict__ order,
                                                const float* __restrict__ val,
                                                const int* __restrict__ tgt,
                                                const int* __restrict__ base,
                                                const unsigned* __restrict__ elist,
                                                const float* __restrict__ Wo,
                                                float* __restrict__ logits_bp) {
    __shared__ float Acc[32 * 256];     // 32-row chunk of Hh pre-activation
    __shared__ float val_s[NK];
    __shared__ int   node_s[NK];
    __shared__ int   tgt_s[NK];
    __shared__ float hvec[DHID];
    int bp = blockIdx.x;
    int hh = bp >> 8, b = (bp >> 5) & 7, blk = bp & 31;
    int ph = (b << 2) | hh;
    int tid = threadIdx.x;
    if (tid < NK) {
        int p = blk * NK + tid;
        node_s[tid] = order[ph * NN + p];
        val_s[tid]  = val[ph * NN + p];
        tgt_s[tid]  = tgt[ph * NN + p];
    }
    __syncthreads();
    int e0 = base[bp], e1 = base[bp + 1];
    int wave = tid >> 6, lane = tid & 63;
    float hsum = 0.f;
    for (int chunk = 0; chunk < 4; ++chunk) {
        for (int t4 = tid; t4 < 32 * 64; t4 += 256)
            ((float4*)Acc)[t4] = float4{0.f, 0.f, 0.f, 0.f};
        __syncthreads();
        for (int t = e0; t < e1; ++t) {
            unsigned ent = elist[t];
            int ss = ent & 0xffff, sd = ent >> 16;
            int is_ = tgt_s[ss];
            if ((is_ >> 5) != chunk) continue;
            if ((is_ & 3) != wave) continue;          // row-disjoint across waves: race-free
            float coef = val_s[ss] * val_s[sd] * val_s[sd];
            int nd = node_s[sd];
            const float4 v = *(const float4*)(G + ((size_t)(b * NN + nd)) * DHID + lane * 4);
            float* mp = Acc + (is_ & 31) * 256 + lane * 4;
            mp[0] += coef * v.x; mp[1] += coef * v.y;
            mp[2] += coef * v.z; mp[3] += coef * v.w;
        }
        __syncthreads();
#pragma unroll
        for (int r = 0; r < 32; ++r) hsum += fmaxf(Acc[r * 256 + tid], 0.f);
        __syncthreads();
    }
    hvec[tid] = hsum * (1.0f / NK);
    __syncthreads();
    if (tid < NCLS) {
        float s = 0.f;
        for (int q = 0; q < DHID; ++q) s = fmaf(hvec[q], Wo[q * NCLS + tid], s);
        logits_bp[bp * NCLS + tid] = s;
    }
}

// head-mean + log_softmax -> (8,32,16)
__global__ void k10_final(const float* __restrict__ logits_bp, float* __restrict__ out) {
    int t = threadIdx.x;                 // 256 = 8*32
    int b = t >> 5, blk = t & 31;
    float v[NCLS];
#pragma unroll
    for (int c = 0; c < NCLS; ++c) {
        float s = 0.f;
        for (int hh = 0; hh < NH; ++hh)
            s += logits_bp[(((hh * NB + b) * NJ) + blk) * NCLS + c];
        v[c] = s * 0.25f;
    }
    float mx = v[0];
#pragma unroll
    for (int c = 1; c < NCLS; ++c) mx = fmaxf(mx, v[c]);
    float se = 0.f;
#pragma unroll
    for (int c = 0; c < NCLS; ++c) se += expf(v[c] - mx);
    float lse = logf(se);
#pragma unroll
    for (int c = 0; c < NCLS; ++c) out[t * NCLS + c] = v[c] - mx - lse;
}

extern "C" void kernel_launch(void* const* d_in, const int* in_sizes, int n_in,
                              void* d_out, int out_size, void* d_ws, size_t ws_size,
                              hipStream_t stream) {
    const float* x  = (const float*)d_in[0];
    const float* wr = (const float*)d_in[1];
    const float* W1 = (const float*)d_in[2];
    const float* Wo = (const float*)d_in[3];
    const int*   ei = (const int*)d_in[4];

    char* ws = (char*)d_ws;
    int*      deg_i      = (int*)(ws + 0);          // 131072 B
    float*    scores_pre = (float*)(ws + 131072);   // 524288 B
    int*      iscore     = (int*)(ws + 655360);     // 524288 B
    float*    xapp       = (float*)(ws + 1179648);  // 16 MB
    float*    G          = (float*)(ws + 17956864); // 33.5 MB
    int*      order      = (int*)(ws + 51511296);   // 524288 B
    int*      pos        = (int*)(ws + 52035584);
    int*      tgt        = (int*)(ws + 52559872);
    float*    val        = (float*)(ws + 53084160);
    int*      cnt        = (int*)(ws + 53608448);   // 4096 B
    int*      fill       = (int*)(ws + 53612544);   // 4096 B
    int*      base       = (int*)(ws + 53616640);   // 4100 B (pad to 8192)
    unsigned* elist      = (unsigned*)(ws + 53624832); // 8 MB (exact worst case E*H)
    float*    logits_bp  = (float*)(ws + 62013440); // 65536 B

    k0_init<<<512, 256, 0, stream>>>(deg_i, iscore, cnt, fill);
    k1_deg<<<2048, 256, 0, stream>>>(ei, deg_i);
    k2_scores<<<512, 256, 0, stream>>>(x, wr, scores_pre);
    k2b_xinit<<<4096, 256, 0, stream>>>(x, deg_i, xapp);
    k3_scatter_scores<<<8192, 256, 0, stream>>>(ei, deg_i, scores_pre, iscore);
    k4_scatter_x<<<65536, 256, 0, stream>>>(ei, deg_i, x, xapp);
    kg_gemm<<<NTOT / 16, 256, 0, stream>>>(x, xapp, W1, G);
    k5_sort<<<32, 1024, 0, stream>>>(scores_pre, iscore, deg_i, order, pos, tgt, val);
    k6_count<<<2048, 256, 0, stream>>>(ei, pos, cnt);
    k7_scan<<<1, 1024, 0, stream>>>(cnt, base);
    k8_fill<<<2048, 256, 0, stream>>>(ei, pos, base, fill, elist);
    k9_block<<<BPB, 256, 0, stream>>>(G, order, val, tgt, base, elist, Wo, logits_bp);
    k10_final<<<1, 256, 0, stream>>>(logits_bp, (float*)d_out);
}

// Round 2
// 474.777 us; speedup vs baseline: 2.6882x; 2.6882x over previous
//
#include <hip/hip_runtime.h>
#include <cmath>

#define NB 8
#define NN 4096
#define DF 128
#define NH 4
#define NJ 32
#define NK 128
#define NTOT (NB*NN)          // 32768
#define ETOT 524288           // 8 * 4096 * 16
#define BPB (NH*NB*NJ)        // 1024
#define DHID 256
#define NCLS 16

#define FP_SCALE 4194304.0    // 2^22 fixed-point for deterministic score scatter
#define FP_INV   (1.0/4194304.0)

// ---------------- init ----------------
__global__ void k0_init(int* deg_i, int* iscore, int* cnt, int* fill, int* fill2) {
    int t = blockIdx.x * blockDim.x + threadIdx.x;
    if (t < NTOT * NH) iscore[t] = 0;
    if (t < NTOT) { deg_i[t] = 0; fill2[t] = 0; }
    if (t < BPB) { cnt[t] = 0; fill[t] = 0; }
}

// in-degree (int, exact, deterministic)
__global__ void k1_deg(const int* __restrict__ ei, int* deg_i) {
    int e = blockIdx.x * blockDim.x + threadIdx.x;
    if (e >= ETOT) return;
    atomicAdd(&deg_i[ei[ETOT + e]], 1);
}

// rdeg = 1/sqrt(1+indeg)
__global__ void k1b_rdeg(const int* __restrict__ deg_i, float* __restrict__ rdeg) {
    int t = blockIdx.x * blockDim.x + threadIdx.x;
    if (t >= NTOT) return;
    rdeg[t] = 1.0f / sqrtf((float)(1 + deg_i[t]));
}

// scores_pre = x_flat @ W_rank  (double accum: minimizes sort-flip risk)
__global__ void k2_scores(const float* __restrict__ x, const float* __restrict__ wr,
                          float* __restrict__ scores_pre) {
    int t = blockIdx.x * blockDim.x + threadIdx.x;
    if (t >= NTOT * NH) return;
    int g = t >> 2, hh = t & 3;
    const float* xr = x + (size_t)g * DF;
    double acc = 0.0;
    for (int d0 = 0; d0 < DF; ++d0) acc += (double)xr[d0] * (double)wr[d0 * NH + hh];
    scores_pre[t] = (float)acc;
}

// score scatter: out[dst] += w * scores_pre[src]  (fixed-point int atomics -> deterministic)
__global__ void k3_scatter_scores(const int* __restrict__ ei, const int* __restrict__ deg_i,
                                  const float* __restrict__ scores_pre, int* iscore) {
    int t = blockIdx.x * blockDim.x + threadIdx.x;
    if (t >= ETOT * NH) return;
    int e = t >> 2, hh = t & 3;
    int s = ei[e], d = ei[ETOT + e];
    double w = 1.0 / sqrt((double)((1 + deg_i[s]) * (1 + deg_i[d])));
    double term = w * (double)scores_pre[s * NH + hh];
    atomicAdd(&iscore[d * NH + hh], __double2int_rn(term * FP_SCALE));
}

// exclusive scan of in-degrees over 32768 nodes (single block)
__global__ __launch_bounds__(1024) void k3b_scan(const int* __restrict__ deg_i, int* nbase) {
    __shared__ int part[1024];
    int t = threadIdx.x;
    int base0 = t * 32;
    int local[32];
    int s = 0;
#pragma unroll
    for (int i = 0; i < 32; ++i) { local[i] = s; s += deg_i[base0 + i]; }
    part[t] = s;
    __syncthreads();
    for (int off = 1; off < 1024; off <<= 1) {
        int v = (t >= off) ? part[t - off] : 0;
        __syncthreads();
        part[t] += v;
        __syncthreads();
    }
    int myoff = (t == 0) ? 0 : part[t - 1];
#pragma unroll
    for (int i = 0; i < 32; ++i) nbase[base0 + i] = myoff + local[i];
    if (t == 1023) nbase[NTOT] = part[1023];
}

// fill dst-CSR: csr_src[nbase[d] + slot] = s
__global__ void k3c_fill_csr(const int* __restrict__ ei, const int* __restrict__ nbase,
                             int* fill2, int* __restrict__ csr_src) {
    int e = blockIdx.x * blockDim.x + threadIdx.x;
    if (e >= ETOT) return;
    int s = ei[e], d = ei[ETOT + e];
    int slot = atomicAdd(&fill2[d], 1);
    csr_src[nbase[d] + slot] = s;
}

// gather: xapp[g,:] = x[g,:]/deg + sum_{s in N(g)} rdeg[g]*rdeg[s]*x[s,:]
// one wave per node; lane i owns columns i and i+64
__global__ __launch_bounds__(256) void k4_gather(const int* __restrict__ csr_src,
                                                 const int* __restrict__ nbase,
                                                 const float* __restrict__ rdeg,
                                                 const float* __restrict__ x,
                                                 float* __restrict__ xapp) {
    int wv = (blockIdx.x * 256 + threadIdx.x) >> 6;   // node id
    if (wv >= NTOT) return;
    int lane = threadIdx.x & 63;
    float rd = rdeg[wv];
    float acc0 = x[(size_t)wv * DF + lane] * rd * rd;        // diagonal: x/deg
    float acc1 = x[(size_t)wv * DF + 64 + lane] * rd * rd;
    int t0 = nbase[wv], t1 = nbase[wv + 1];
    for (int t = t0; t < t1; ++t) {
        int s = csr_src[t];
        float w = rd * rdeg[s];
        acc0 += w * x[(size_t)s * DF + lane];
        acc1 += w * x[(size_t)s * DF + 64 + lane];
    }
    xapp[(size_t)wv * DF + lane] = acc0;
    xapp[(size_t)wv * DF + 64 + lane] = acc1;
}

// G = concat(x, xapp) @ W1   (32768 x 256) -- 16-row tiles, f32
__global__ __launch_bounds__(256) void kg_gemm(const float* __restrict__ x,
                                               const float* __restrict__ xapp,
                                               const float* __restrict__ W1,
                                               float* __restrict__ G) {
    __shared__ float fs[16 * 256];
    int g0 = blockIdx.x * 16;
    int tid = threadIdx.x;
    for (int t = tid; t < 16 * 64; t += 256) {
        int r = t >> 6, q4 = t & 63;
        int g = g0 + r;
        const float* src = (q4 < 32) ? (x + (size_t)g * DF + q4 * 4)
                                     : (xapp + (size_t)g * DF + (q4 - 32) * 4);
        ((float4*)fs)[t] = *(const float4*)src;
    }
    __syncthreads();
    int c = tid;
    float acc[16];
#pragma unroll
    for (int ii = 0; ii < 16; ++ii) acc[ii] = 0.f;
    for (int q4 = 0; q4 < 64; ++q4) {
        int q = q4 * 4;
        float w0 = W1[(q + 0) * DHID + c];
        float w1 = W1[(q + 1) * DHID + c];
        float w2 = W1[(q + 2) * DHID + c];
        float w3 = W1[(q + 3) * DHID + c];
#pragma unroll
        for (int ii = 0; ii < 16; ++ii) {
            float4 m4 = *(const float4*)(fs + ii * 256 + q);
            acc[ii] = fmaf(m4.x, w0, acc[ii]);
            acc[ii] = fmaf(m4.y, w1, acc[ii]);
            acc[ii] = fmaf(m4.z, w2, acc[ii]);
            acc[ii] = fmaf(m4.w, w3, acc[ii]);
        }
    }
#pragma unroll
    for (int ii = 0; ii < 16; ++ii) G[((size_t)(g0 + ii)) * DHID + c] = acc[ii];
}

// per-(b,head) stable bitonic sort of 4096 scores (desc score, asc idx) + pos/val/tgt
__global__ __launch_bounds__(1024) void k5_sort(const float* __restrict__ scores_pre,
                                                const int* __restrict__ iscore,
                                                const int* __restrict__ deg_i,
                                                int* order, int* pos, int* tgt, float* val) {
    __shared__ float key[NN];
    __shared__ int   idx[NN];
    int bid = blockIdx.x;            // b*4 + hh
    int b = bid >> 2, hh = bid & 3;
    int tid = threadIdx.x;
    for (int p = tid; p < NN; p += 1024) {
        int g = b * NN + p;
        float dg = (float)(1 + deg_i[g]);
        key[p] = scores_pre[g * NH + hh] / dg + (float)((double)iscore[g * NH + hh] * FP_INV);
        idx[p] = p;
    }
    __syncthreads();
    for (int size = 2; size <= NN; size <<= 1) {
        for (int stride = size >> 1; stride > 0; stride >>= 1) {
            for (int p = tid; p < NN; p += 1024) {
                int q = p ^ stride;
                if (q > p) {
                    float kp = key[p], kq = key[q];
                    int ip = idx[p], iq = idx[q];
                    bool before_qp = (kq > kp) || (kq == kp && iq < ip);
                    bool asc = ((p & size) == 0);
                    if (asc ? before_qp : !before_qp) {
                        key[p] = kq; key[q] = kp; idx[p] = iq; idx[q] = ip;
                    }
                }
            }
            __syncthreads();
        }
    }
    for (int p = tid; p < NN; p += 1024) {
        int o = idx[p];
        order[bid * NN + p] = o;
        pos[bid * NN + o] = p;
        float sc = key[p];
        val[bid * NN + p] = 1.0f / (1.0f + expf(-sc));
    }
    __syncthreads();
    for (int p = tid; p < NN; p += 1024) {
        int base0 = p & ~(NK - 1);
        int me = idx[p];
        int r = 0;
        for (int s2 = 0; s2 < NK; ++s2) r += (idx[base0 + s2] < me) ? 1 : 0;
        tgt[bid * NN + p] = r;
    }
}

// count kept (same-block) edge-head pairs per block
__global__ void k6_count(const int* __restrict__ ei, const int* __restrict__ pos, int* cnt) {
    int e = blockIdx.x * blockDim.x + threadIdx.x;
    if (e >= ETOT) return;
    int s = ei[e], d = ei[ETOT + e];
    int b = s >> 12, sl = s & 4095, dl = d & 4095;
#pragma unroll
    for (int hh = 0; hh < NH; ++hh) {
        int ph = (b << 2) | hh;
        int ps = pos[ph * NN + sl], pd = pos[ph * NN + dl];
        if ((ps >> 7) == (pd >> 7))
            atomicAdd(&cnt[((hh * NB + b) * NJ) + (ps >> 7)], 1);
    }
}

__global__ __launch_bounds__(1024) void k7_scan(const int* __restrict__ cnt, int* base) {
    __shared__ int sh[BPB];
    int t = threadIdx.x;
    sh[t] = cnt[t];
    __syncthreads();
    for (int off = 1; off < BPB; off <<= 1) {
        int v = (t >= off) ? sh[t - off] : 0;
        __syncthreads();
        sh[t] += v;
        __syncthreads();
    }
    base[t + 1] = sh[t];
    if (t == 0) base[0] = 0;
}

__global__ void k8_fill(const int* __restrict__ ei, const int* __restrict__ pos,
                        const int* __restrict__ base, int* fill, unsigned* elist) {
    int e = blockIdx.x * blockDim.x + threadIdx.x;
    if (e >= ETOT) return;
    int s = ei[e], d = ei[ETOT + e];
    int b = s >> 12, sl = s & 4095, dl = d & 4095;
#pragma unroll
    for (int hh = 0; hh < NH; ++hh) {
        int ph = (b << 2) | hh;
        int ps = pos[ph * NN + sl], pd = pos[ph * NN + dl];
        if ((ps >> 7) == (pd >> 7)) {
            int bpid = ((hh * NB + b) * NJ) + (ps >> 7);
            int k2 = atomicAdd(&fill[bpid], 1);
            elist[base[bpid] + k2] = (unsigned)((ps & 127) | ((pd & 127) << 16));
        }
    }
}

// per-block: Hh rows = relu(sum_edges coef * G[node_d,:]), mean over 128 rows, @ W_out
__global__ __launch_bounds__(256) void k9_block(const float* __restrict__ G,
                                                const int* __restrict__ order,
                                                const float* __restrict__ val,
                                                const int* __restrict__ tgt,
                                                const int* __restrict__ base,
                                                const unsigned* __restrict__ elist,
                                                const float* __restrict__ Wo,
                                                float* __restrict__ logits_bp) {
    __shared__ float Acc[32 * 256];     // 32-row chunk of Hh pre-activation
    __shared__ float val_s[NK];
    __shared__ int   node_s[NK];
    __shared__ int   tgt_s[NK];
    __shared__ float hvec[DHID];
    int bp = blockIdx.x;
    int hh = bp >> 8, b = (bp >> 5) & 7, blk = bp & 31;
    int ph = (b << 2) | hh;
    int tid = threadIdx.x;
    if (tid < NK) {
        int p = blk * NK + tid;
        node_s[tid] = order[ph * NN + p];
        val_s[tid]  = val[ph * NN + p];
        tgt_s[tid]  = tgt[ph * NN + p];
    }
    __syncthreads();
    int e0 = base[bp], e1 = base[bp + 1];
    int wave = tid >> 6, lane = tid & 63;
    float hsum = 0.f;
    for (int chunk = 0; chunk < 4; ++chunk) {
        for (int t4 = tid; t4 < 32 * 64; t4 += 256)
            ((float4*)Acc)[t4] = float4{0.f, 0.f, 0.f, 0.f};
        __syncthreads();
        for (int t = e0; t < e1; ++t) {
            unsigned ent = elist[t];
            int ss = ent & 0xffff, sd = ent >> 16;
            int is_ = tgt_s[ss];
            if ((is_ >> 5) != chunk) continue;
            if ((is_ & 3) != wave) continue;          // row-disjoint across waves: race-free
            float coef = val_s[ss] * val_s[sd] * val_s[sd];
            int nd = node_s[sd];
            const float4 v = *(const float4*)(G + ((size_t)(b * NN + nd)) * DHID + lane * 4);
            float* mp = Acc + (is_ & 31) * 256 + lane * 4;
            mp[0] += coef * v.x; mp[1] += coef * v.y;
            mp[2] += coef * v.z; mp[3] += coef * v.w;
        }
        __syncthreads();
#pragma unroll
        for (int r = 0; r < 32; ++r) hsum += fmaxf(Acc[r * 256 + tid], 0.f);
        __syncthreads();
    }
    hvec[tid] = hsum * (1.0f / NK);
    __syncthreads();
    if (tid < NCLS) {
        float s = 0.f;
        for (int q = 0; q < DHID; ++q) s = fmaf(hvec[q], Wo[q * NCLS + tid], s);
        logits_bp[bp * NCLS + tid] = s;
    }
}

// head-mean + log_softmax -> (8,32,16)
__global__ void k10_final(const float* __restrict__ logits_bp, float* __restrict__ out) {
    int t = threadIdx.x;                 // 256 = 8*32
    int b = t >> 5, blk = t & 31;
    float v[NCLS];
#pragma unroll
    for (int c = 0; c < NCLS; ++c) {
        float s = 0.f;
        for (int hh = 0; hh < NH; ++hh)
            s += logits_bp[(((hh * NB + b) * NJ) + blk) * NCLS + c];
        v[c] = s * 0.25f;
    }
    float mx = v[0];
#pragma unroll
    for (int c = 1; c < NCLS; ++c) mx = fmaxf(mx, v[c]);
    float se = 0.f;
#pragma unroll
    for (int c = 0; c < NCLS; ++c) se += expf(v[c] - mx);
    float lse = logf(se);
#pragma unroll
    for (int c = 0; c < NCLS; ++c) out[t * NCLS + c] = v[c] - mx - lse;
}

extern "C" void kernel_launch(void* const* d_in, const int* in_sizes, int n_in,
                              void* d_out, int out_size, void* d_ws, size_t ws_size,
                              hipStream_t stream) {
    const float* x  = (const float*)d_in[0];
    const float* wr = (const float*)d_in[1];
    const float* W1 = (const float*)d_in[2];
    const float* Wo = (const float*)d_in[3];
    const int*   ei = (const int*)d_in[4];

    char* ws = (char*)d_ws;
    int*      deg_i      = (int*)(ws + 0);          // 128 KB
    float*    rdeg       = (float*)(ws + 131072);   // 128 KB
    float*    scores_pre = (float*)(ws + 262144);   // 512 KB
    int*      iscore     = (int*)(ws + 786432);     // 512 KB
    float*    xapp       = (float*)(ws + 1310720);  // 16 MB
    float*    G          = (float*)(ws + 18087936); // 32 MB
    int*      order      = (int*)(ws + 51642368);   // 512 KB
    int*      pos        = (int*)(ws + 52166656);
    int*      tgt        = (int*)(ws + 52690944);
    float*    val        = (float*)(ws + 53215232);
    int*      cnt        = (int*)(ws + 53739520);   // 4 KB
    int*      fill       = (int*)(ws + 53743616);   // 4 KB
    int*      base       = (int*)(ws + 53747712);   // 8 KB
    unsigned* elist      = (unsigned*)(ws + 53755904); // 8 MB
    int*      csr_src    = (int*)(ws + 53755904);   // 2 MB (aliases elist: disjoint lifetime)
    float*    logits_bp  = (float*)(ws + 62144512); // 64 KB
    int*      nbase      = (int*)(ws + 62210048);   // 128 KB + 4
    int*      fill2      = (int*)(ws + 62341184);   // 128 KB

    k0_init<<<512, 256, 0, stream>>>(deg_i, iscore, cnt, fill, fill2);
    k1_deg<<<2048, 256, 0, stream>>>(ei, deg_i);
    k1b_rdeg<<<128, 256, 0, stream>>>(deg_i, rdeg);
    k2_scores<<<512, 256, 0, stream>>>(x, wr, scores_pre);
    k3_scatter_scores<<<8192, 256, 0, stream>>>(ei, deg_i, scores_pre, iscore);
    k3b_scan<<<1, 1024, 0, stream>>>(deg_i, nbase);
    k3c_fill_csr<<<2048, 256, 0, stream>>>(ei, nbase, fill2, csr_src);
    k4_gather<<<8192, 256, 0, stream>>>(csr_src, nbase, rdeg, x, xapp);
    kg_gemm<<<NTOT / 16, 256, 0, stream>>>(x, xapp, W1, G);
    k5_sort<<<32, 1024, 0, stream>>>(scores_pre, iscore, deg_i, order, pos, tgt, val);
    k6_count<<<2048, 256, 0, stream>>>(ei, pos, cnt);
    k7_scan<<<1, 1024, 0, stream>>>(cnt, base);
    k8_fill<<<2048, 256, 0, stream>>>(ei, pos, base, fill, elist);
    k9_block<<<BPB, 256, 0, stream>>>(G, order, val, tgt, base, elist, Wo, logits_bp);
    k10_final<<<1, 256, 0, stream>>>(logits_bp, (float*)d_out);
}

// Round 3
// 434.434 us; speedup vs baseline: 2.9378x; 1.0929x over previous
//
#include <hip/hip_runtime.h>
#include <cmath>

#define NB 8
#define NN 4096
#define DF 128
#define NH 4
#define NJ 32
#define NK 128
#define NTOT (NB*NN)          // 32768
#define ETOT 524288           // 8 * 4096 * 16
#define BPB (NH*NB*NJ)        // 1024
#define DHID 256
#define NCLS 16

#define FP_SCALE 4194304.0    // 2^22 fixed-point for deterministic score scatter
#define FP_INV   (1.0/4194304.0)

typedef short bf16x8 __attribute__((ext_vector_type(8)));
typedef float f32x4  __attribute__((ext_vector_type(4)));

__device__ __forceinline__ unsigned short f2bf(float f) {
    unsigned u = __float_as_uint(f);
    unsigned r = (u + 0x7FFFu + ((u >> 16) & 1u)) >> 16;   // RNE
    return (unsigned short)r;
}

// ---------------- init ----------------
__global__ void k0_init(int* deg_i, int* iscore, int* cnt, int* fill, int* fill2) {
    int t = blockIdx.x * blockDim.x + threadIdx.x;
    if (t < NTOT * NH) iscore[t] = 0;
    if (t < NTOT) { deg_i[t] = 0; fill2[t] = 0; }
    if (t < BPB) { cnt[t] = 0; fill[t] = 0; }
}

// in-degree (int, exact, deterministic)
__global__ void k1_deg(const int* __restrict__ ei, int* deg_i) {
    int e = blockIdx.x * blockDim.x + threadIdx.x;
    if (e >= ETOT) return;
    atomicAdd(&deg_i[ei[ETOT + e]], 1);
}

// rdeg = 1/sqrt(1+indeg)
__global__ void k1b_rdeg(const int* __restrict__ deg_i, float* __restrict__ rdeg) {
    int t = blockIdx.x * blockDim.x + threadIdx.x;
    if (t >= NTOT) return;
    rdeg[t] = 1.0f / sqrtf((float)(1 + deg_i[t]));
}

// W1T_bf[n][k] = bf16(W1[k][n])   (256x256, coalesced reads)
__global__ void kw_w1t(const float* __restrict__ W1, unsigned short* __restrict__ w1t) {
    int t = blockIdx.x * 256 + threadIdx.x;     // 65536
    int k = t >> 8, n = t & 255;
    w1t[n * 256 + k] = f2bf(W1[k * DHID + n]);
}

// scores_pre = x_flat @ W_rank  (double accum: minimizes sort-flip risk)
__global__ void k2_scores(const float* __restrict__ x, const float* __restrict__ wr,
                          float* __restrict__ scores_pre) {
    int t = blockIdx.x * blockDim.x + threadIdx.x;
    if (t >= NTOT * NH) return;
    int g = t >> 2, hh = t & 3;
    const float* xr = x + (size_t)g * DF;
    double acc = 0.0;
    for (int d0 = 0; d0 < DF; ++d0) acc += (double)xr[d0] * (double)wr[d0 * NH + hh];
    scores_pre[t] = (float)acc;
}

// score scatter: fixed-point int atomics -> deterministic
__global__ void k3_scatter_scores(const int* __restrict__ ei, const int* __restrict__ deg_i,
                                  const float* __restrict__ scores_pre, int* iscore) {
    int t = blockIdx.x * blockDim.x + threadIdx.x;
    if (t >= ETOT * NH) return;
    int e = t >> 2, hh = t & 3;
    int s = ei[e], d = ei[ETOT + e];
    double w = 1.0 / sqrt((double)((1 + deg_i[s]) * (1 + deg_i[d])));
    double term = w * (double)scores_pre[s * NH + hh];
    atomicAdd(&iscore[d * NH + hh], __double2int_rn(term * FP_SCALE));
}

// exclusive scan of in-degrees over 32768 nodes (single block)
__global__ __launch_bounds__(1024) void k3b_scan(const int* __restrict__ deg_i, int* nbase) {
    __shared__ int part[1024];
    int t = threadIdx.x;
    int base0 = t * 32;
    int local[32];
    int s = 0;
#pragma unroll
    for (int i = 0; i < 32; ++i) { local[i] = s; s += deg_i[base0 + i]; }
    part[t] = s;
    __syncthreads();
    for (int off = 1; off < 1024; off <<= 1) {
        int v = (t >= off) ? part[t - off] : 0;
        __syncthreads();
        part[t] += v;
        __syncthreads();
    }
    int myoff = (t == 0) ? 0 : part[t - 1];
#pragma unroll
    for (int i = 0; i < 32; ++i) nbase[base0 + i] = myoff + local[i];
    if (t == 1023) nbase[NTOT] = part[1023];
}

// fill dst-CSR: csr_src[nbase[d] + slot] = s
__global__ void k3c_fill_csr(const int* __restrict__ ei, const int* __restrict__ nbase,
                             int* fill2, int* __restrict__ csr_src) {
    int e = blockIdx.x * blockDim.x + threadIdx.x;
    if (e >= ETOT) return;
    int s = ei[e], d = ei[ETOT + e];
    int slot = atomicAdd(&fill2[d], 1);
    csr_src[nbase[d] + slot] = s;
}

// gather: xapp[g,:] = x[g,:]/deg + sum_{s in N(g)} rdeg[g]*rdeg[s]*x[s,:]
__global__ __launch_bounds__(256) void k4_gather(const int* __restrict__ csr_src,
                                                 const int* __restrict__ nbase,
                                                 const float* __restrict__ rdeg,
                                                 const float* __restrict__ x,
                                                 float* __restrict__ xapp) {
    int wv = (blockIdx.x * 256 + threadIdx.x) >> 6;   // node id
    if (wv >= NTOT) return;
    int lane = threadIdx.x & 63;
    float rd = rdeg[wv];
    float acc0 = x[(size_t)wv * DF + lane] * rd * rd;
    float acc1 = x[(size_t)wv * DF + 64 + lane] * rd * rd;
    int t0 = nbase[wv], t1 = nbase[wv + 1];
    for (int t = t0; t < t1; ++t) {
        int s = csr_src[t];
        float w = rd * rdeg[s];
        acc0 += w * x[(size_t)s * DF + lane];
        acc1 += w * x[(size_t)s * DF + 64 + lane];
    }
    xapp[(size_t)wv * DF + lane] = acc0;
    xapp[(size_t)wv * DF + 64 + lane] = acc1;
}

// G = concat(x, xapp) @ W1 via bf16 MFMA.  M=32768, N=256, K=256.
// 128x128 tile, 4 waves (2x2), BK=64, XOR-swizzled LDS (16B granules).
__global__ __launch_bounds__(256) void kg_mfma(const float* __restrict__ x,
                                               const float* __restrict__ xapp,
                                               const unsigned short* __restrict__ w1t,
                                               float* __restrict__ G) {
    __shared__ __align__(16) unsigned short As[128 * 64];  // [row][k] swizzled
    __shared__ __align__(16) unsigned short Bs[128 * 64];  // [n][k]   swizzled
    int bid = blockIdx.x;
    int m0 = (bid >> 1) * 128, n0 = (bid & 1) * 128;
    int tid = threadIdx.x, lane = tid & 63, wid = tid >> 6;
    int wr = wid >> 1, wc = wid & 1;
    f32x4 acc[4][4];
#pragma unroll
    for (int mi = 0; mi < 4; ++mi)
#pragma unroll
        for (int ni = 0; ni < 4; ++ni) acc[mi][ni] = f32x4{0.f, 0.f, 0.f, 0.f};

    for (int kk = 0; kk < 4; ++kk) {
        int k0 = kk * 64;
        const float* Asrc = (k0 < 128) ? x : xapp;
        int kbase = k0 & 127;
        // stage A: cvt f32->bf16, write to swizzled granule (involution c^(r&7))
#pragma unroll
        for (int i = 0; i < 4; ++i) {
            int gi = tid + i * 256;
            int r = gi >> 3, c = gi & 7;
            int csrc = c ^ (r & 7);
            const float* sp = Asrc + (size_t)(m0 + r) * DF + kbase + csrc * 8;
            float4 lo = *(const float4*)sp;
            float4 hi = *(const float4*)(sp + 4);
            unsigned short u[8] = {f2bf(lo.x), f2bf(lo.y), f2bf(lo.z), f2bf(lo.w),
                                   f2bf(hi.x), f2bf(hi.y), f2bf(hi.z), f2bf(hi.w)};
            *(bf16x8*)&As[r * 64 + c * 8] = *(bf16x8*)u;
        }
        // stage B from bf16 W1T
#pragma unroll
        for (int i = 0; i < 4; ++i) {
            int gi = tid + i * 256;
            int r = gi >> 3, c = gi & 7;
            int csrc = c ^ (r & 7);
            *(bf16x8*)&Bs[r * 64 + c * 8] =
                *(const bf16x8*)(w1t + (size_t)(n0 + r) * 256 + k0 + csrc * 8);
        }
        __syncthreads();
#pragma unroll
        for (int ks = 0; ks < 2; ++ks) {
            bf16x8 af[4], bfr[4];
#pragma unroll
            for (int mi = 0; mi < 4; ++mi) {
                int r = wr * 64 + mi * 16 + (lane & 15);
                int gl = ks * 4 + (lane >> 4);
                af[mi] = *(const bf16x8*)&As[r * 64 + (gl ^ (r & 7)) * 8];
            }
#pragma unroll
            for (int ni = 0; ni < 4; ++ni) {
                int r = wc * 64 + ni * 16 + (lane & 15);
                int gl = ks * 4 + (lane >> 4);
                bfr[ni] = *(const bf16x8*)&Bs[r * 64 + (gl ^ (r & 7)) * 8];
            }
#pragma unroll
            for (int mi = 0; mi < 4; ++mi)
#pragma unroll
                for (int ni = 0; ni < 4; ++ni)
                    acc[mi][ni] = __builtin_amdgcn_mfma_f32_16x16x32_bf16(
                        af[mi], bfr[ni], acc[mi][ni], 0, 0, 0);
        }
        __syncthreads();
    }
    // epilogue: C/D layout col=lane&15, row=(lane>>4)*4+j
#pragma unroll
    for (int mi = 0; mi < 4; ++mi) {
        int rbase = m0 + wr * 64 + mi * 16 + (lane >> 4) * 4;
#pragma unroll
        for (int ni = 0; ni < 4; ++ni) {
            int col = n0 + wc * 64 + ni * 16 + (lane & 15);
#pragma unroll
            for (int j = 0; j < 4; ++j)
                G[(size_t)(rbase + j) * DHID + col] = acc[mi][ni][j];
        }
    }
}

// per-(b,head) stable bitonic sort of 4096 scores (desc score, asc idx) + pos/val/tgt
__global__ __launch_bounds__(1024) void k5_sort(const float* __restrict__ scores_pre,
                                                const int* __restrict__ iscore,
                                                const int* __restrict__ deg_i,
                                                int* order, int* pos, int* tgt, float* val) {
    __shared__ float key[NN];
    __shared__ int   idx[NN];
    int bid = blockIdx.x;            // b*4 + hh
    int b = bid >> 2, hh = bid & 3;
    int tid = threadIdx.x;
    for (int p = tid; p < NN; p += 1024) {
        int g = b * NN + p;
        float dg = (float)(1 + deg_i[g]);
        key[p] = scores_pre[g * NH + hh] / dg + (float)((double)iscore[g * NH + hh] * FP_INV);
        idx[p] = p;
    }
    __syncthreads();
    for (int size = 2; size <= NN; size <<= 1) {
        for (int stride = size >> 1; stride > 0; stride >>= 1) {
            for (int p = tid; p < NN; p += 1024) {
                int q = p ^ stride;
                if (q > p) {
                    float kp = key[p], kq = key[q];
                    int ip = idx[p], iq = idx[q];
                    bool before_qp = (kq > kp) || (kq == kp && iq < ip);
                    bool asc = ((p & size) == 0);
                    if (asc ? before_qp : !before_qp) {
                        key[p] = kq; key[q] = kp; idx[p] = iq; idx[q] = ip;
                    }
                }
            }
            __syncthreads();
        }
    }
    for (int p = tid; p < NN; p += 1024) {
        int o = idx[p];
        order[bid * NN + p] = o;
        pos[bid * NN + o] = p;
        float sc = key[p];
        val[bid * NN + p] = 1.0f / (1.0f + expf(-sc));
    }
    __syncthreads();
    for (int p = tid; p < NN; p += 1024) {
        int base0 = p & ~(NK - 1);
        int me = idx[p];
        int r = 0;
        for (int s2 = 0; s2 < NK; ++s2) r += (idx[base0 + s2] < me) ? 1 : 0;
        tgt[bid * NN + p] = r;
    }
}

// classify each (edge, head): compute block-pair id + slots, count per block, emit record
__global__ void k6_classify(const int* __restrict__ ei, const int* __restrict__ pos,
                            int* cnt, unsigned* __restrict__ rec) {
    int t = blockIdx.x * blockDim.x + threadIdx.x;
    if (t >= ETOT * NH) return;
    int e = t >> 2, hh = t & 3;
    int s = ei[e], d = ei[ETOT + e];
    int b = s >> 12, sl = s & 4095, dl = d & 4095;
    int ph = (b << 2) | hh;
    int ps = pos[ph * NN + sl], pd = pos[ph * NN + dl];
    unsigned r = 0xFFFFFFFFu;
    if ((ps >> 7) == (pd >> 7)) {
        int bpid = ((hh * NB + b) * NJ) + (ps >> 7);
        atomicAdd(&cnt[bpid], 1);
        r = ((unsigned)bpid << 14) | ((unsigned)(ps & 127) << 7) | (unsigned)(pd & 127);
    }
    rec[t] = r;
}

__global__ __launch_bounds__(1024) void k7_scan(const int* __restrict__ cnt, int* base) {
    __shared__ int sh[BPB];
    int t = threadIdx.x;
    sh[t] = cnt[t];
    __syncthreads();
    for (int off = 1; off < BPB; off <<= 1) {
        int v = (t >= off) ? sh[t - off] : 0;
        __syncthreads();
        sh[t] += v;
        __syncthreads();
    }
    base[t + 1] = sh[t];
    if (t == 0) base[0] = 0;
}

__global__ void k8_fill(const unsigned* __restrict__ rec, const int* __restrict__ base,
                        int* fill, unsigned* elist) {
    int t = blockIdx.x * blockDim.x + threadIdx.x;
    if (t >= ETOT * NH) return;
    unsigned r = rec[t];
    if (r == 0xFFFFFFFFu) return;
    int bpid = r >> 14;
    int ss = (r >> 7) & 127, sd = r & 127;
    int k2 = atomicAdd(&fill[bpid], 1);
    elist[base[bpid] + k2] = (unsigned)(ss | (sd << 16));
}

// per-block: Hh rows = relu(sum_edges coef * G[node_d,:]), mean over 128 rows, @ W_out
__global__ __launch_bounds__(256) void k9_block(const float* __restrict__ G,
                                                const int* __restrict__ order,
                                                const float* __restrict__ val,
                                                const int* __restrict__ tgt,
                                                const int* __restrict__ base,
                                                const unsigned* __restrict__ elist,
                                                const float* __restrict__ Wo,
                                                float* __restrict__ logits_bp) {
    __shared__ float Acc[32 * 256];
    __shared__ float val_s[NK];
    __shared__ int   node_s[NK];
    __shared__ int   tgt_s[NK];
    __shared__ float hvec[DHID];
    int bp = blockIdx.x;
    int hh = bp >> 8, b = (bp >> 5) & 7, blk = bp & 31;
    int ph = (b << 2) | hh;
    int tid = threadIdx.x;
    if (tid < NK) {
        int p = blk * NK + tid;
        node_s[tid] = order[ph * NN + p];
        val_s[tid]  = val[ph * NN + p];
        tgt_s[tid]  = tgt[ph * NN + p];
    }
    __syncthreads();
    int e0 = base[bp], e1 = base[bp + 1];
    int wave = tid >> 6, lane = tid & 63;
    float hsum = 0.f;
    for (int chunk = 0; chunk < 4; ++chunk) {
        for (int t4 = tid; t4 < 32 * 64; t4 += 256)
            ((float4*)Acc)[t4] = float4{0.f, 0.f, 0.f, 0.f};
        __syncthreads();
        for (int t = e0; t < e1; ++t) {
            unsigned ent = elist[t];
            int ss = ent & 0xffff, sd = ent >> 16;
            int is_ = tgt_s[ss];
            if ((is_ >> 5) != chunk) continue;
            if ((is_ & 3) != wave) continue;          // row-disjoint across waves: race-free
            float coef = val_s[ss] * val_s[sd] * val_s[sd];
            int nd = node_s[sd];
            const float4 v = *(const float4*)(G + ((size_t)(b * NN + nd)) * DHID + lane * 4);
            float* mp = Acc + (is_ & 31) * 256 + lane * 4;
            mp[0] += coef * v.x; mp[1] += coef * v.y;
            mp[2] += coef * v.z; mp[3] += coef * v.w;
        }
        __syncthreads();
#pragma unroll
        for (int r = 0; r < 32; ++r) hsum += fmaxf(Acc[r * 256 + tid], 0.f);
        __syncthreads();
    }
    hvec[tid] = hsum * (1.0f / NK);
    __syncthreads();
    if (tid < NCLS) {
        float s = 0.f;
        for (int q = 0; q < DHID; ++q) s = fmaf(hvec[q], Wo[q * NCLS + tid], s);
        logits_bp[bp * NCLS + tid] = s;
    }
}

// head-mean + log_softmax -> (8,32,16)
__global__ void k10_final(const float* __restrict__ logits_bp, float* __restrict__ out) {
    int t = threadIdx.x;                 // 256 = 8*32
    int b = t >> 5, blk = t & 31;
    float v[NCLS];
#pragma unroll
    for (int c = 0; c < NCLS; ++c) {
        float s = 0.f;
        for (int hh = 0; hh < NH; ++hh)
            s += logits_bp[(((hh * NB + b) * NJ) + blk) * NCLS + c];
        v[c] = s * 0.25f;
    }
    float mx = v[0];
#pragma unroll
    for (int c = 1; c < NCLS; ++c) mx = fmaxf(mx, v[c]);
    float se = 0.f;
#pragma unroll
    for (int c = 0; c < NCLS; ++c) se += expf(v[c] - mx);
    float lse = logf(se);
#pragma unroll
    for (int c = 0; c < NCLS; ++c) out[t * NCLS + c] = v[c] - mx - lse;
}

extern "C" void kernel_launch(void* const* d_in, const int* in_sizes, int n_in,
                              void* d_out, int out_size, void* d_ws, size_t ws_size,
                              hipStream_t stream) {
    const float* x  = (const float*)d_in[0];
    const float* wr = (const float*)d_in[1];
    const float* W1 = (const float*)d_in[2];
    const float* Wo = (const float*)d_in[3];
    const int*   ei = (const int*)d_in[4];

    char* ws = (char*)d_ws;
    int*      deg_i      = (int*)(ws + 0);          // 128 KB
    float*    rdeg       = (float*)(ws + 131072);   // 128 KB
    float*    scores_pre = (float*)(ws + 262144);   // 512 KB
    int*      iscore     = (int*)(ws + 786432);     // 512 KB
    float*    xapp       = (float*)(ws + 1310720);  // 16 MB
    float*    G          = (float*)(ws + 18087936); // 32 MB
    int*      order      = (int*)(ws + 51642368);   // 512 KB
    int*      pos        = (int*)(ws + 52166656);
    int*      tgt        = (int*)(ws + 52690944);
    float*    val        = (float*)(ws + 53215232);
    int*      cnt        = (int*)(ws + 53739520);   // 4 KB
    int*      fill       = (int*)(ws + 53743616);   // 4 KB
    int*      base       = (int*)(ws + 53747712);   // 8 KB
    int*      csr_src    = (int*)(ws + 53755904);   // 2 MB (lifetime ends at k4)
    unsigned short* w1t  = (unsigned short*)(ws + 55853056); // 128 KB (dead before elist writes)
    unsigned* elist      = (unsigned*)(ws + 53755904); // 8 MB (aliases csr_src+w1t; written at k8)
    float*    logits_bp  = (float*)(ws + 62144512); // 64 KB
    int*      nbase      = (int*)(ws + 62210048);   // 128 KB + 4
    int*      fill2      = (int*)(ws + 62341184);   // 128 KB
    unsigned* rec        = (unsigned*)xapp;         // 8 MB, aliases xapp (dead after kg_mfma)

    k0_init<<<512, 256, 0, stream>>>(deg_i, iscore, cnt, fill, fill2);
    k1_deg<<<2048, 256, 0, stream>>>(ei, deg_i);
    k1b_rdeg<<<128, 256, 0, stream>>>(deg_i, rdeg);
    kw_w1t<<<256, 256, 0, stream>>>(W1, w1t);
    k2_scores<<<512, 256, 0, stream>>>(x, wr, scores_pre);
    k3_scatter_scores<<<8192, 256, 0, stream>>>(ei, deg_i, scores_pre, iscore);
    k3b_scan<<<1, 1024, 0, stream>>>(deg_i, nbase);
    k3c_fill_csr<<<2048, 256, 0, stream>>>(ei, nbase, fill2, csr_src);
    k4_gather<<<8192, 256, 0, stream>>>(csr_src, nbase, rdeg, x, xapp);
    kg_mfma<<<512, 256, 0, stream>>>(x, xapp, w1t, G);        // consumes xapp, w1t
    k5_sort<<<32, 1024, 0, stream>>>(scores_pre, iscore, deg_i, order, pos, tgt, val);
    k6_classify<<<8192, 256, 0, stream>>>(ei, pos, cnt, rec); // rec overwrites xapp (dead)
    k7_scan<<<1, 1024, 0, stream>>>(cnt, base);
    k8_fill<<<8192, 256, 0, stream>>>(rec, base, fill, elist); // elist overwrites csr/w1t (dead)
    k9_block<<<BPB, 256, 0, stream>>>(G, order, val, tgt, base, elist, Wo, logits_bp);
    k10_final<<<1, 256, 0, stream>>>(logits_bp, (float*)d_out);
}

// Round 4
// 393.630 us; speedup vs baseline: 3.2424x; 1.1037x over previous
//
#include <hip/hip_runtime.h>
#include <cmath>

#define NB 8
#define NN 4096
#define DF 128
#define NH 4
#define NJ 32
#define NK 128
#define NTOT (NB*NN)          // 32768
#define ETOT 524288           // 8 * 4096 * 16
#define BPB (NH*NB*NJ)        // 1024
#define DHID 256
#define NCLS 16

#define FP_SCALE 4194304.0    // 2^22 fixed-point for deterministic score scatter
#define FP_INV   (1.0/4194304.0)

typedef short bf16x8 __attribute__((ext_vector_type(8)));
typedef float f32x4  __attribute__((ext_vector_type(4)));

__device__ __forceinline__ unsigned short f2bf(float f) {
    unsigned u = __float_as_uint(f);
    unsigned r = (u + 0x7FFFu + ((u >> 16) & 1u)) >> 16;   // RNE
    return (unsigned short)r;
}

// sortable u64 key: ascending k64 == (descending score, ascending idx) — matches argsort(-s) stable
__device__ __forceinline__ unsigned long long make_key(float sc, int p) {
    unsigned u = __float_as_uint(sc);
    unsigned s = u ^ ((unsigned)((int)u >> 31) | 0x80000000u);   // ascending-float map
    return ((unsigned long long)(s ^ 0xFFFFFFFFu) << 12) | (unsigned)p;
}

// ---------------- init ----------------
__global__ void k0_init(int* deg_i, int* iscore, int* cnt, int* fill, int* fill2) {
    int t = blockIdx.x * blockDim.x + threadIdx.x;
    if (t < NTOT * NH) iscore[t] = 0;
    if (t < NTOT) { deg_i[t] = 0; fill2[t] = 0; }
    if (t < BPB) { cnt[t] = 0; fill[t] = 0; }
}

// in-degree (int, exact, deterministic)
__global__ void k1_deg(const int* __restrict__ ei, int* deg_i) {
    int e = blockIdx.x * blockDim.x + threadIdx.x;
    if (e >= ETOT) return;
    atomicAdd(&deg_i[ei[ETOT + e]], 1);
}

// rdeg = 1/sqrt(1+indeg)
__global__ void k1b_rdeg(const int* __restrict__ deg_i, float* __restrict__ rdeg) {
    int t = blockIdx.x * blockDim.x + threadIdx.x;
    if (t >= NTOT) return;
    rdeg[t] = 1.0f / sqrtf((float)(1 + deg_i[t]));
}

// W1T_bf[n][k] = bf16(W1[k][n])   (256x256, coalesced reads)
__global__ void kw_w1t(const float* __restrict__ W1, unsigned short* __restrict__ w1t) {
    int t = blockIdx.x * 256 + threadIdx.x;     // 65536
    int k = t >> 8, n = t & 255;
    w1t[n * 256 + k] = f2bf(W1[k * DHID + n]);
}

// scores_pre = x_flat @ W_rank  (double accum: minimizes sort-flip risk)
__global__ void k2_scores(const float* __restrict__ x, const float* __restrict__ wr,
                          float* __restrict__ scores_pre) {
    int t = blockIdx.x * blockDim.x + threadIdx.x;
    if (t >= NTOT * NH) return;
    int g = t >> 2, hh = t & 3;
    const float* xr = x + (size_t)g * DF;
    double acc = 0.0;
    for (int d0 = 0; d0 < DF; ++d0) acc += (double)xr[d0] * (double)wr[d0 * NH + hh];
    scores_pre[t] = (float)acc;
}

// score scatter: fixed-point int atomics -> deterministic (f32 weight; quantization dominates)
__global__ void k3_scatter_scores(const int* __restrict__ ei, const float* __restrict__ rdeg,
                                  const float* __restrict__ scores_pre, int* iscore) {
    int t = blockIdx.x * blockDim.x + threadIdx.x;
    if (t >= ETOT * NH) return;
    int e = t >> 2, hh = t & 3;
    int s = ei[e], d = ei[ETOT + e];
    float w = rdeg[s] * rdeg[d];
    double term = (double)(w * scores_pre[s * NH + hh]);
    atomicAdd(&iscore[d * NH + hh], __double2int_rn(term * FP_SCALE));
}

// exclusive scan of in-degrees over 32768 nodes (single block)
__global__ __launch_bounds__(1024) void k3b_scan(const int* __restrict__ deg_i, int* nbase) {
    __shared__ int part[1024];
    int t = threadIdx.x;
    int base0 = t * 32;
    int local[32];
    int s = 0;
#pragma unroll
    for (int i = 0; i < 32; ++i) { local[i] = s; s += deg_i[base0 + i]; }
    part[t] = s;
    __syncthreads();
    for (int off = 1; off < 1024; off <<= 1) {
        int v = (t >= off) ? part[t - off] : 0;
        __syncthreads();
        part[t] += v;
        __syncthreads();
    }
    int myoff = (t == 0) ? 0 : part[t - 1];
#pragma unroll
    for (int i = 0; i < 32; ++i) nbase[base0 + i] = myoff + local[i];
    if (t == 1023) nbase[NTOT] = part[1023];
}

// fill dst-CSR: csr_src[nbase[d] + slot] = s
__global__ void k3c_fill_csr(const int* __restrict__ ei, const int* __restrict__ nbase,
                             int* fill2, int* __restrict__ csr_src) {
    int e = blockIdx.x * blockDim.x + threadIdx.x;
    if (e >= ETOT) return;
    int s = ei[e], d = ei[ETOT + e];
    int slot = atomicAdd(&fill2[d], 1);
    csr_src[nbase[d] + slot] = s;
}

// gather: xapp[g,:] = x[g,:]/deg + sum_{s in N(g)} rdeg[g]*rdeg[s]*x[s,:]
__global__ __launch_bounds__(256) void k4_gather(const int* __restrict__ csr_src,
                                                 const int* __restrict__ nbase,
                                                 const float* __restrict__ rdeg,
                                                 const float* __restrict__ x,
                                                 float* __restrict__ xapp) {
    int wv = (blockIdx.x * 256 + threadIdx.x) >> 6;   // node id
    if (wv >= NTOT) return;
    int lane = threadIdx.x & 63;
    float rd = rdeg[wv];
    float acc0 = x[(size_t)wv * DF + lane] * rd * rd;
    float acc1 = x[(size_t)wv * DF + 64 + lane] * rd * rd;
    int t0 = nbase[wv], t1 = nbase[wv + 1];
    for (int t = t0; t < t1; ++t) {
        int s = csr_src[t];
        float w = rd * rdeg[s];
        acc0 += w * x[(size_t)s * DF + lane];
        acc1 += w * x[(size_t)s * DF + 64 + lane];
    }
    xapp[(size_t)wv * DF + lane] = acc0;
    xapp[(size_t)wv * DF + 64 + lane] = acc1;
}

// G = concat(x, xapp) @ W1 via bf16 MFMA.  M=32768, N=256, K=256.
__global__ __launch_bounds__(256) void kg_mfma(const float* __restrict__ x,
                                               const float* __restrict__ xapp,
                                               const unsigned short* __restrict__ w1t,
                                               float* __restrict__ G) {
    __shared__ __align__(16) unsigned short As[128 * 64];  // [row][k] swizzled
    __shared__ __align__(16) unsigned short Bs[128 * 64];  // [n][k]   swizzled
    int bid = blockIdx.x;
    int m0 = (bid >> 1) * 128, n0 = (bid & 1) * 128;
    int tid = threadIdx.x, lane = tid & 63, wid = tid >> 6;
    int wr = wid >> 1, wc = wid & 1;
    f32x4 acc[4][4];
#pragma unroll
    for (int mi = 0; mi < 4; ++mi)
#pragma unroll
        for (int ni = 0; ni < 4; ++ni) acc[mi][ni] = f32x4{0.f, 0.f, 0.f, 0.f};

    for (int kk = 0; kk < 4; ++kk) {
        int k0 = kk * 64;
        const float* Asrc = (k0 < 128) ? x : xapp;
        int kbase = k0 & 127;
#pragma unroll
        for (int i = 0; i < 4; ++i) {
            int gi = tid + i * 256;
            int r = gi >> 3, c = gi & 7;
            int csrc = c ^ (r & 7);
            const float* sp = Asrc + (size_t)(m0 + r) * DF + kbase + csrc * 8;
            float4 lo = *(const float4*)sp;
            float4 hi = *(const float4*)(sp + 4);
            unsigned short u[8] = {f2bf(lo.x), f2bf(lo.y), f2bf(lo.z), f2bf(lo.w),
                                   f2bf(hi.x), f2bf(hi.y), f2bf(hi.z), f2bf(hi.w)};
            *(bf16x8*)&As[r * 64 + c * 8] = *(bf16x8*)u;
        }
#pragma unroll
        for (int i = 0; i < 4; ++i) {
            int gi = tid + i * 256;
            int r = gi >> 3, c = gi & 7;
            int csrc = c ^ (r & 7);
            *(bf16x8*)&Bs[r * 64 + c * 8] =
                *(const bf16x8*)(w1t + (size_t)(n0 + r) * 256 + k0 + csrc * 8);
        }
        __syncthreads();
#pragma unroll
        for (int ks = 0; ks < 2; ++ks) {
            bf16x8 af[4], bfr[4];
#pragma unroll
            for (int mi = 0; mi < 4; ++mi) {
                int r = wr * 64 + mi * 16 + (lane & 15);
                int gl = ks * 4 + (lane >> 4);
                af[mi] = *(const bf16x8*)&As[r * 64 + (gl ^ (r & 7)) * 8];
            }
#pragma unroll
            for (int ni = 0; ni < 4; ++ni) {
                int r = wc * 64 + ni * 16 + (lane & 15);
                int gl = ks * 4 + (lane >> 4);
                bfr[ni] = *(const bf16x8*)&Bs[r * 64 + (gl ^ (r & 7)) * 8];
            }
#pragma unroll
            for (int mi = 0; mi < 4; ++mi)
#pragma unroll
                for (int ni = 0; ni < 4; ++ni)
                    acc[mi][ni] = __builtin_amdgcn_mfma_f32_16x16x32_bf16(
                        af[mi], bfr[ni], acc[mi][ni], 0, 0, 0);
        }
        __syncthreads();
    }
#pragma unroll
    for (int mi = 0; mi < 4; ++mi) {
        int rbase = m0 + wr * 64 + mi * 16 + (lane >> 4) * 4;
#pragma unroll
        for (int ni = 0; ni < 4; ++ni) {
            int col = n0 + wc * 64 + ni * 16 + (lane & 15);
#pragma unroll
            for (int j = 0; j < 4; ++j)
                G[(size_t)(rbase + j) * DHID + col] = acc[mi][ni][j];
        }
    }
}

// sort phase A: 512-element chunk bitonic sort on packed u64 keys (one block per chunk)
__global__ __launch_bounds__(256) void k5a_chunk(const float* __restrict__ scores_pre,
                                                 const int* __restrict__ iscore,
                                                 const int* __restrict__ deg_i,
                                                 unsigned long long* __restrict__ sorted64) {
    __shared__ unsigned long long sk[512];
    int blk = blockIdx.x;            // seg*8 + chunk
    int seg = blk >> 3, chunk = blk & 7;
    int b = seg >> 2, hh = seg & 3;
    int tid = threadIdx.x;
    for (int i = tid; i < 512; i += 256) {
        int p = chunk * 512 + i;
        int g = b * NN + p;
        float dg = (float)(1 + deg_i[g]);
        float sc = scores_pre[g * NH + hh] / dg + (float)((double)iscore[g * NH + hh] * FP_INV);
        sk[i] = make_key(sc, p);
    }
    __syncthreads();
    for (int size = 2; size <= 512; size <<= 1) {
        for (int stride = size >> 1; stride > 0; stride >>= 1) {
            for (int p = tid; p < 512; p += 256) {
                int q = p ^ stride;
                if (q > p) {
                    unsigned long long kp = sk[p], kq = sk[q];
                    bool before_qp = (kq < kp);
                    bool asc = ((p & size) == 0);
                    if (asc ? before_qp : !before_qp) { sk[p] = kq; sk[q] = kp; }
                }
            }
            __syncthreads();
        }
    }
    for (int i = tid; i < 512; i += 256)
        sorted64[seg * NN + chunk * 512 + i] = sk[i];
}

// sort phase B: rank via binary searches over the other 7 sorted chunks (no barriers)
__global__ __launch_bounds__(256) void k5b_rank(const unsigned long long* __restrict__ sorted64,
                                                int* __restrict__ order, int* __restrict__ pos,
                                                float* __restrict__ val) {
    int t = blockIdx.x * 256 + threadIdx.x;      // 131072
    int seg = t >> 12, i = t & 4095;
    int chunk = i >> 9, slot = i & 511;
    const unsigned long long* segp = sorted64 + (size_t)seg * NN;
    unsigned long long k = segp[chunk * 512 + slot];
    int rank = slot;
#pragma unroll
    for (int c = 0; c < 8; ++c) {
        if (c == chunk) continue;
        const unsigned long long* cp = segp + c * 512;
        int lo = 0, hi = 512;
        while (lo < hi) { int mid = (lo + hi) >> 1; lo = (cp[mid] < k) ? mid + 1 : lo; hi = (cp[mid] < k) ? hi : mid; }
        rank += lo;
    }
    int p = (int)(k & 4095u);
    pos[seg * NN + p] = rank;
    order[seg * NN + rank] = p;
    unsigned s = (unsigned)(k >> 12) ^ 0xFFFFFFFFu;
    unsigned u = s ^ (((int)s >= 0) ? 0xFFFFFFFFu : 0x80000000u);
    float sc = __uint_as_float(u);
    val[seg * NN + rank] = 1.0f / (1.0f + expf(-sc));
}

// sort phase C: tgt = rank of order[p] by node-id within its 128-block
__global__ __launch_bounds__(128) void k5c_tgt(const int* __restrict__ order,
                                               int* __restrict__ tgt) {
    __shared__ int o[128];
    int base = blockIdx.x * 128;     // = seg*4096 + j*128
    int tid = threadIdx.x;
    o[tid] = order[base + tid];
    __syncthreads();
    int me = o[tid];
    int r = 0;
#pragma unroll 16
    for (int s2 = 0; s2 < 128; ++s2) r += (o[s2] < me) ? 1 : 0;
    tgt[base + tid] = r;
}

// classify each (edge, head): compute block-pair id + slots, count per block, emit record
__global__ void k6_classify(const int* __restrict__ ei, const int* __restrict__ pos,
                            int* cnt, unsigned* __restrict__ rec) {
    int t = blockIdx.x * blockDim.x + threadIdx.x;
    if (t >= ETOT * NH) return;
    int e = t >> 2, hh = t & 3;
    int s = ei[e], d = ei[ETOT + e];
    int b = s >> 12, sl = s & 4095, dl = d & 4095;
    int ph = (b << 2) | hh;
    int ps = pos[ph * NN + sl], pd = pos[ph * NN + dl];
    unsigned r = 0xFFFFFFFFu;
    if ((ps >> 7) == (pd >> 7)) {
        int bpid = ((hh * NB + b) * NJ) + (ps >> 7);
        atomicAdd(&cnt[bpid], 1);
        r = ((unsigned)bpid << 14) | ((unsigned)(ps & 127) << 7) | (unsigned)(pd & 127);
    }
    rec[t] = r;
}

__global__ __launch_bounds__(1024) void k7_scan(const int* __restrict__ cnt, int* base) {
    __shared__ int sh[BPB];
    int t = threadIdx.x;
    sh[t] = cnt[t];
    __syncthreads();
    for (int off = 1; off < BPB; off <<= 1) {
        int v = (t >= off) ? sh[t - off] : 0;
        __syncthreads();
        sh[t] += v;
        __syncthreads();
    }
    base[t + 1] = sh[t];
    if (t == 0) base[0] = 0;
}

__global__ void k8_fill(const unsigned* __restrict__ rec, const int* __restrict__ base,
                        int* fill, unsigned* elist) {
    int t = blockIdx.x * blockDim.x + threadIdx.x;
    if (t >= ETOT * NH) return;
    unsigned r = rec[t];
    if (r == 0xFFFFFFFFu) return;
    int bpid = r >> 14;
    int ss = (r >> 7) & 127, sd = r & 127;
    int k2 = atomicAdd(&fill[bpid], 1);
    elist[base[bpid] + k2] = (unsigned)(ss | (sd << 16));
}

// per-block: Hh rows = relu(sum_edges coef * G[node_d,:]), mean over 128 rows, @ W_out
__global__ __launch_bounds__(256) void k9_block(const float* __restrict__ G,
                                                const int* __restrict__ order,
                                                const float* __restrict__ val,
                                                const int* __restrict__ tgt,
                                                const int* __restrict__ base,
                                                const unsigned* __restrict__ elist,
                                                const float* __restrict__ Wo,
                                                float* __restrict__ logits_bp) {
    __shared__ float Acc[32 * 256];
    __shared__ float val_s[NK];
    __shared__ int   node_s[NK];
    __shared__ int   tgt_s[NK];
    __shared__ float hvec[DHID];
    int bp = blockIdx.x;
    int hh = bp >> 8, b = (bp >> 5) & 7, blk = bp & 31;
    int ph = (b << 2) | hh;
    int tid = threadIdx.x;
    if (tid < NK) {
        int p = blk * NK + tid;
        node_s[tid] = order[ph * NN + p];
        val_s[tid]  = val[ph * NN + p];
        tgt_s[tid]  = tgt[ph * NN + p];
    }
    __syncthreads();
    int e0 = base[bp], e1 = base[bp + 1];
    int wave = tid >> 6, lane = tid & 63;
    float hsum = 0.f;
    for (int chunk = 0; chunk < 4; ++chunk) {
        for (int t4 = tid; t4 < 32 * 64; t4 += 256)
            ((float4*)Acc)[t4] = float4{0.f, 0.f, 0.f, 0.f};
        __syncthreads();
        for (int t = e0; t < e1; ++t) {
            unsigned ent = elist[t];
            int ss = ent & 0xffff, sd = ent >> 16;
            int is_ = tgt_s[ss];
            if ((is_ >> 5) != chunk) continue;
            if ((is_ & 3) != wave) continue;          // row-disjoint across waves: race-free
            float coef = val_s[ss] * val_s[sd] * val_s[sd];
            int nd = node_s[sd];
            const float4 v = *(const float4*)(G + ((size_t)(b * NN + nd)) * DHID + lane * 4);
            float* mp = Acc + (is_ & 31) * 256 + lane * 4;
            mp[0] += coef * v.x; mp[1] += coef * v.y;
            mp[2] += coef * v.z; mp[3] += coef * v.w;
        }
        __syncthreads();
#pragma unroll
        for (int r = 0; r < 32; ++r) hsum += fmaxf(Acc[r * 256 + tid], 0.f);
        __syncthreads();
    }
    hvec[tid] = hsum * (1.0f / NK);
    __syncthreads();
    if (tid < NCLS) {
        float s = 0.f;
        for (int q = 0; q < DHID; ++q) s = fmaf(hvec[q], Wo[q * NCLS + tid], s);
        logits_bp[bp * NCLS + tid] = s;
    }
}

// head-mean + log_softmax -> (8,32,16)
__global__ void k10_final(const float* __restrict__ logits_bp, float* __restrict__ out) {
    int t = threadIdx.x;                 // 256 = 8*32
    int b = t >> 5, blk = t & 31;
    float v[NCLS];
#pragma unroll
    for (int c = 0; c < NCLS; ++c) {
        float s = 0.f;
        for (int hh = 0; hh < NH; ++hh)
            s += logits_bp[(((hh * NB + b) * NJ) + blk) * NCLS + c];
        v[c] = s * 0.25f;
    }
    float mx = v[0];
#pragma unroll
    for (int c = 1; c < NCLS; ++c) mx = fmaxf(mx, v[c]);
    float se = 0.f;
#pragma unroll
    for (int c = 0; c < NCLS; ++c) se += expf(v[c] - mx);
    float lse = logf(se);
#pragma unroll
    for (int c = 0; c < NCLS; ++c) out[t * NCLS + c] = v[c] - mx - lse;
}

extern "C" void kernel_launch(void* const* d_in, const int* in_sizes, int n_in,
                              void* d_out, int out_size, void* d_ws, size_t ws_size,
                              hipStream_t stream) {
    const float* x  = (const float*)d_in[0];
    const float* wr = (const float*)d_in[1];
    const float* W1 = (const float*)d_in[2];
    const float* Wo = (const float*)d_in[3];
    const int*   ei = (const int*)d_in[4];

    char* ws = (char*)d_ws;
    int*      deg_i      = (int*)(ws + 0);          // 128 KB
    float*    rdeg       = (float*)(ws + 131072);   // 128 KB
    float*    scores_pre = (float*)(ws + 262144);   // 512 KB
    int*      iscore     = (int*)(ws + 786432);     // 512 KB
    float*    xapp       = (float*)(ws + 1310720);  // 16 MB
    float*    G          = (float*)(ws + 18087936); // 32 MB
    int*      order      = (int*)(ws + 51642368);   // 512 KB
    int*      pos        = (int*)(ws + 52166656);
    int*      tgt        = (int*)(ws + 52690944);
    float*    val        = (float*)(ws + 53215232);
    int*      cnt        = (int*)(ws + 53739520);   // 4 KB
    int*      fill       = (int*)(ws + 53743616);   // 4 KB
    int*      base       = (int*)(ws + 53747712);   // 8 KB
    int*      csr_src    = (int*)(ws + 53755904);   // 2 MB (lifetime ends at k4)
    unsigned short* w1t  = (unsigned short*)(ws + 55853056); // 128 KB (dead before elist writes)
    unsigned* elist      = (unsigned*)(ws + 53755904); // 8 MB (aliases csr_src+w1t; written at k8)
    float*    logits_bp  = (float*)(ws + 62144512); // 64 KB
    int*      nbase      = (int*)(ws + 62210048);   // 128 KB + 4
    int*      fill2      = (int*)(ws + 62341184);   // 128 KB
    unsigned* rec        = (unsigned*)xapp;                            // 8 MB  (xapp[0..8M), dead after kg_mfma)
    unsigned long long* sorted64 = (unsigned long long*)(ws + 9699328); // 1 MB (xapp[8M..9M), dead after kg_mfma)

    k0_init<<<512, 256, 0, stream>>>(deg_i, iscore, cnt, fill, fill2);
    k1_deg<<<2048, 256, 0, stream>>>(ei, deg_i);
    k1b_rdeg<<<128, 256, 0, stream>>>(deg_i, rdeg);
    kw_w1t<<<256, 256, 0, stream>>>(W1, w1t);
    k2_scores<<<512, 256, 0, stream>>>(x, wr, scores_pre);
    k3_scatter_scores<<<8192, 256, 0, stream>>>(ei, rdeg, scores_pre, iscore);
    k3b_scan<<<1, 1024, 0, stream>>>(deg_i, nbase);
    k3c_fill_csr<<<2048, 256, 0, stream>>>(ei, nbase, fill2, csr_src);
    k4_gather<<<8192, 256, 0, stream>>>(csr_src, nbase, rdeg, x, xapp);
    kg_mfma<<<512, 256, 0, stream>>>(x, xapp, w1t, G);        // last consumer of xapp
    k5a_chunk<<<256, 256, 0, stream>>>(scores_pre, iscore, deg_i, sorted64);
    k5b_rank<<<512, 256, 0, stream>>>(sorted64, order, pos, val);
    k5c_tgt<<<1024, 128, 0, stream>>>(order, tgt);
    k6_classify<<<8192, 256, 0, stream>>>(ei, pos, cnt, rec); // rec overwrites xapp (dead)
    k7_scan<<<1, 1024, 0, stream>>>(cnt, base);
    k8_fill<<<8192, 256, 0, stream>>>(rec, base, fill, elist); // elist overwrites csr/w1t (dead)
    k9_block<<<BPB, 256, 0, stream>>>(G, order, val, tgt, base, elist, Wo, logits_bp);
    k10_final<<<1, 256, 0, stream>>>(logits_bp, (float*)d_out);
}